// Round 1
// baseline (409.179 us; speedup 1.0000x reference)
//
#include <hip/hip_runtime.h>

typedef unsigned short u16;
typedef __bf16 bf16x8 __attribute__((ext_vector_type(8)));
typedef float f32x4 __attribute__((ext_vector_type(4)));

#define E_ 1024
#define T_ 2048
#define B_ 2
#define H_ 16
#define FF_ 4096
#define M_ 4096   // B*T

__device__ __forceinline__ u16 f2b(float f) {
    union { float f; unsigned u; } c; c.f = f;
    unsigned r = c.u + 0x7FFFu + ((c.u >> 16) & 1u);
    return (u16)(r >> 16);
}
// truncating f32->bf16 (1 op); used where downstream normalization cancels bias
__device__ __forceinline__ u16 f2bt(float f) {
    union { float f; unsigned u; } c; c.f = f;
    return (u16)(c.u >> 16);
}

// async global->LDS, 16B per lane; LDS dest = wave-uniform base + lane*16
__device__ __forceinline__ void gl16(const u16* g, u16* l) {
    __builtin_amdgcn_global_load_lds(
        (__attribute__((address_space(1))) void*)g,
        (__attribute__((address_space(3))) void*)l, 16, 0, 0);
}

// ---------------- fused weight/bias conversion + LN1 ----------------
__global__ __launch_bounds__(256) void cvt_ln(
        const float* __restrict__ Wq, const float* __restrict__ Wk,
        const float* __restrict__ Wv, const float* __restrict__ Wo,
        const float* __restrict__ W1, const float* __restrict__ W2,
        const float* __restrict__ bq, const float* __restrict__ bk,
        const float* __restrict__ bv,
        u16* __restrict__ WqkvB, u16* __restrict__ WoB,
        u16* __restrict__ W1B, u16* __restrict__ W2B,
        float* __restrict__ bqkv,
        const float* __restrict__ x, const float* __restrict__ g1,
        const float* __restrict__ b1v, u16* __restrict__ hB) {
    if (blockIdx.x < 1024) {
        int row = blockIdx.x * 4 + (threadIdx.x >> 6);
        int t = threadIdx.x & 63;
        const float* xr = x + (size_t)row * E_;
        float v[16];
        float sum = 0.f, ss = 0.f;
#pragma unroll
        for (int c = 0; c < 4; c++) {
            float4 f = *(const float4*)&xr[c * 256 + t * 4];
            v[c * 4 + 0] = f.x; v[c * 4 + 1] = f.y; v[c * 4 + 2] = f.z; v[c * 4 + 3] = f.w;
            sum += f.x + f.y + f.z + f.w;
            ss += f.x * f.x + f.y * f.y + f.z * f.z + f.w * f.w;
        }
#pragma unroll
        for (int d = 32; d; d >>= 1) {
            sum += __shfl_xor(sum, d);
            ss  += __shfl_xor(ss, d);
        }
        float mu = sum * (1.f / E_);
        float var = ss * (1.f / E_) - mu * mu;
        float rs = rsqrtf(var + 1e-5f);
#pragma unroll
        for (int c = 0; c < 4; c++) {
            int idx = c * 256 + t * 4;
            float4 g4 = *(const float4*)&g1[idx];
            float4 b4 = *(const float4*)&b1v[idx];
            ushort4 o;
            o.x = f2b((v[c * 4 + 0] - mu) * rs * g4.x + b4.x);
            o.y = f2b((v[c * 4 + 1] - mu) * rs * g4.y + b4.y);
            o.z = f2b((v[c * 4 + 2] - mu) * rs * g4.z + b4.z);
            o.w = f2b((v[c * 4 + 3] - mu) * rs * g4.w + b4.w);
            *(ushort4*)&hB[(size_t)row * E_ + idx] = o;
        }
        return;
    }
    int i = (blockIdx.x - 1024) * 256 + threadIdx.x;
    if (i >= 3146496) return;
    if (i >= 3145728) {             // biases (fp32 copy)
        int j = i - 3145728;        // 0..767
        const float* s = (j < 256) ? bq : (j < 512) ? bk : bv;
        int jj = j & 255;
        *(float4*)&bqkv[j * 4] = *(const float4*)&s[jj * 4];
        return;
    }
    const float* src; u16* dst; int j;
    if (i < 786432) {
        src = (i < 262144) ? Wq : (i < 524288) ? Wk : Wv;
        j = i & 262143;
        dst = WqkvB + (i >> 18) * (E_ * E_);
    } else if (i < 1048576) { j = i - 786432;  src = Wo; dst = WoB; }
    else if (i < 2097152)   { j = i - 1048576; src = W1; dst = W1B; }
    else                    { j = i - 2097152; src = W2; dst = W2B; }
    float4 f = *(const float4*)&src[j * 4];
    ushort4 o;
    o.x = f2b(f.x); o.y = f2b(f.y); o.z = f2b(f.z); o.w = f2b(f.w);
    *(ushort4*)&dst[j * 4] = o;
}

// ---------------- LayerNorm: 1 wave per row of 1024 ----------------
__global__ __launch_bounds__(64) void ln_fwd(u16* __restrict__ out, const float* __restrict__ x,
                                             const float* __restrict__ g, const float* __restrict__ bta) {
    int row = blockIdx.x;
    int t = threadIdx.x;
    const float* xr = x + (size_t)row * E_;
    float v[16];
    float sum = 0.f, ss = 0.f;
#pragma unroll
    for (int c = 0; c < 4; c++) {
        float4 f = *(const float4*)&xr[c * 256 + t * 4];
        v[c * 4 + 0] = f.x; v[c * 4 + 1] = f.y; v[c * 4 + 2] = f.z; v[c * 4 + 3] = f.w;
        sum += f.x + f.y + f.z + f.w;
        ss += f.x * f.x + f.y * f.y + f.z * f.z + f.w * f.w;
    }
#pragma unroll
    for (int d = 32; d; d >>= 1) {
        sum += __shfl_xor(sum, d);
        ss  += __shfl_xor(ss, d);
    }
    float mu = sum * (1.f / E_);
    float var = ss * (1.f / E_) - mu * mu;
    float rs = rsqrtf(var + 1e-5f);
#pragma unroll
    for (int c = 0; c < 4; c++) {
        int idx = c * 256 + t * 4;
        float4 g4 = *(const float4*)&g[idx];
        float4 b4 = *(const float4*)&bta[idx];
        ushort4 o;
        o.x = f2b((v[c * 4 + 0] - mu) * rs * g4.x + b4.x);
        o.y = f2b((v[c * 4 + 1] - mu) * rs * g4.y + b4.y);
        o.z = f2b((v[c * 4 + 2] - mu) * rs * g4.z + b4.z);
        o.w = f2b((v[c * 4 + 3] - mu) * rs * g4.w + b4.w);
        *(ushort4*)&out[(size_t)row * E_ + idx] = o;
    }
}

// ---------------- bf16 MFMA GEMM, 3-stage counted-vmcnt pipeline ----------------
// C[M,N] = A[M,K] * Bt[N,K]^T. BMx128 tile (BM=128 or 64), 256 thr (2x2 waves), BK=32.
// T4 technique: raw s_barrier + s_waitcnt vmcnt(NL) so loads for tiles k+1,k+2 stay
// in flight across the barrier (2-iteration latency window instead of the compiler's
// vmcnt(0) drain at __syncthreads). vmcnt(0) only on the peeled last iteration.
template<int BM>
__global__ __launch_bounds__(256) void gemm_bt(
        const u16* __restrict__ A, const u16* __restrict__ Bt,
        const float* __restrict__ bias, const float* __restrict__ residual,
        float* __restrict__ outF, u16* __restrict__ outB, u16* __restrict__ outVt,
        int M, int N, int K, int relu, int qkvmode) {
    constexpr int MT = BM / 32;          // m-frags per wave (128->4, 64->2)
    __shared__ __align__(16) u16 As[3][BM * 32];
    __shared__ __align__(16) u16 Bs[3][128 * 32];
    int tid = threadIdx.x;
    int m0 = blockIdx.y * BM, n0 = blockIdx.x * 128;
    int wave = tid >> 6, lane = tid & 63;
    int wm = wave & 1, wn = wave >> 1;
    int r16 = lane & 15, kg = lane >> 4;

    const u16* gA = A + (size_t)(m0 + wave * (BM / 4) + (lane >> 2)) * K + (lane & 3) * 8;
    const u16* gB = Bt + (size_t)(n0 + wave * 32 + (lane >> 2)) * K + (lane & 3) * 8;
    size_t row16 = (size_t)16 * K;
    int aoff = wave * (BM / 4) * 32;
    int boff = wave * 1024;

    f32x4 acc[MT][4] = {};

    const int nk = K >> 5;              // >= 32 for all call sites

    auto issue = [&](int kt, int buf) {
        int k1 = kt << 5;
        gl16(gA + k1, As[buf] + aoff);
        if (BM == 128) gl16(gA + k1 + row16, As[buf] + aoff + 512);
        gl16(gB + k1, Bs[buf] + boff);
        gl16(gB + k1 + row16, Bs[buf] + boff + 512);
    };

    auto compute = [&](int cb) {
        bf16x8 af[MT], bfr[4];
#pragma unroll
        for (int mt = 0; mt < MT; mt++)
            af[mt] = *(const bf16x8*)&As[cb][(wm * (BM / 2) + mt * 16 + r16) * 32 + kg * 8];
#pragma unroll
        for (int nt = 0; nt < 4; nt++)
            bfr[nt] = *(const bf16x8*)&Bs[cb][(wn * 64 + nt * 16 + r16) * 32 + kg * 8];
#pragma unroll
        for (int mt = 0; mt < MT; mt++)
#pragma unroll
            for (int nt = 0; nt < 4; nt++)
                acc[mt][nt] = __builtin_amdgcn_mfma_f32_16x16x32_bf16(af[mt], bfr[nt], acc[mt][nt], 0, 0, 0);
    };

    issue(0, 0);
    issue(1, 1);

    int cur = 0;
    for (int ks = 0; ks < nk - 1; ks++) {
        // loads(ks) + loads(ks+1) in flight (NL each); keep loads(ks+1) flying.
        if (BM == 128) asm volatile("s_waitcnt vmcnt(4)" ::: "memory");
        else           asm volatile("s_waitcnt vmcnt(3)" ::: "memory");
        __builtin_amdgcn_s_barrier();
        asm volatile("" ::: "memory");
        if (ks + 2 < nk) {
            int p2 = cur ? cur - 1 : 2;     // (cur+2)%3 — buffer read 1 iter ago
            issue(ks + 2, p2);
        }
        compute(cur);
        cur = (cur < 2) ? cur + 1 : 0;
    }
    asm volatile("s_waitcnt vmcnt(0)" ::: "memory");
    __builtin_amdgcn_s_barrier();
    asm volatile("" ::: "memory");
    compute(cur);

#pragma unroll
    for (int mt = 0; mt < MT; mt++) {
#pragma unroll
        for (int nt = 0; nt < 4; nt++) {
            int gm = m0 + wm * (BM / 2) + mt * 16 + kg * 4;
            int gn = n0 + wn * 64 + nt * 16 + r16;
            float bv = bias[gn];
            if (qkvmode) {
                if (gn < 2048) {
                    // Q prescale: 1/sqrt(64) * log2(e)  (attn softmax runs in exp2 domain)
                    float scl = (gn < 1024) ? 0.18033688f : 1.0f;
#pragma unroll
                    for (int r = 0; r < 4; r++)
                        outB[(size_t)(gm + r) * 2048 + gn] = f2b((acc[mt][nt][r] + bv) * scl);
                } else {
                    int bq_ = gm >> 11, tq = gm & 2047, d = gn - 2048;
                    ushort4 ov;
                    ov.x = f2b(acc[mt][nt][0] + bv);
                    ov.y = f2b(acc[mt][nt][1] + bv);
                    ov.z = f2b(acc[mt][nt][2] + bv);
                    ov.w = f2b(acc[mt][nt][3] + bv);
                    *(ushort4*)&outVt[((size_t)(bq_ * 1024 + d)) * 2048 + tq] = ov;
                }
            } else {
#pragma unroll
                for (int r = 0; r < 4; r++) {
                    float v = acc[mt][nt][r] + bv;
                    size_t off = (size_t)(gm + r) * N + gn;
                    if (residual) v += residual[off];
                    if (relu) v = fmaxf(v, 0.f);
                    if (outF) outF[off] = v;
                    else outB[off] = f2b(v);
                }
            }
        }
    }
}

// ---------------- MFMA flash attention (bf16, causal, FIXED-SHIFT exp2 softmax) -----
// softmax is shift-invariant; scores in log2 domain have std~0.5, max<<16 (LN'd
// inputs x uniform(1/32) weights). Fixed shift c=16 (folded into MFMA C-init)
// removes ALL online-softmax bookkeeping: no max tree, no sum tree, no rescale.
// l = per-lane partial, reduced once at the end. Overflow would need s>143.
#define AST 68   // 34 dw stride: bank-conflict-free for all access patterns here
__global__ __launch_bounds__(256) void attn_mfma(
        const u16* __restrict__ qk, const u16* __restrict__ vt,
        u16* __restrict__ out) {
    __shared__ __align__(16) u16 Ks[2][64 * AST];  // K[key][d]
    __shared__ __align__(16) u16 Vs[2][64 * AST];  // Vt[d][key]
    __shared__ __align__(16) u16 Ps[4][16 * AST];  // per-wave P[q][key]

    int bz = blockIdx.x;
    int h  = bz & 15;
    int b  = (bz >> 4) & 1;
    int qt = bz >> 5;

    int tid = threadIdx.x;
    int w = tid >> 6, lane = tid & 63;
    int g = lane >> 4, l16 = lane & 15;

    int qrow = qt * 64 + w * 16 + l16;
    bf16x8 qf[2];
    qf[0] = *(const bf16x8*)&qk[(size_t)(b * T_ + qrow) * 2048 + h * 64 + g * 8];
    qf[1] = *(const bf16x8*)&qk[(size_t)(b * T_ + qrow) * 2048 + h * 64 + 32 + g * 8];

    f32x4 o[4] = {};
    f32x4 lp = {0.f, 0.f, 0.f, 0.f};      // per-lane partial row-sums (index r)

    int r1 = tid >> 3, col1 = (tid & 7) * 8;
    const u16* gK = qk + (size_t)(b * T_) * 2048 + 1024 + h * 64;
    const u16* gV = vt + (size_t)(b * 1024 + h * 64) * 2048;

    uint4 kr1 = *(const uint4*)&gK[(size_t)r1 * 2048 + col1];
    uint4 kr2 = *(const uint4*)&gK[(size_t)(r1 + 32) * 2048 + col1];
    uint4 vr1 = *(const uint4*)&gV[(size_t)r1 * 2048 + col1];
    uint4 vr2 = *(const uint4*)&gV[(size_t)(r1 + 32) * 2048 + col1];

    for (int t = 0; t <= qt; t++) {
        int cur = t & 1;
        *(uint4*)&Ks[cur][r1 * AST + col1] = kr1;
        *(uint4*)&Ks[cur][(r1 + 32) * AST + col1] = kr2;
        *(uint4*)&Vs[cur][r1 * AST + col1] = vr1;
        *(uint4*)&Vs[cur][(r1 + 32) * AST + col1] = vr2;
        __syncthreads();                      // single barrier per tile
        if (t < qt) {                         // issue next-tile loads AFTER barrier
            int j1 = (t + 1) * 64;
            kr1 = *(const uint4*)&gK[(size_t)(j1 + r1) * 2048 + col1];
            kr2 = *(const uint4*)&gK[(size_t)(j1 + r1 + 32) * 2048 + col1];
            vr1 = *(const uint4*)&gV[(size_t)r1 * 2048 + j1 + col1];
            vr2 = *(const uint4*)&gV[(size_t)(r1 + 32) * 2048 + j1 + col1];
        }

        // S - 16 = Q K^T + C(-16)  (C-layout: key = nt*16+l16, q = g*4+r)
        f32x4 s[4];
#pragma unroll
        for (int nt = 0; nt < 4; nt++) {
            f32x4 c16 = {-16.f, -16.f, -16.f, -16.f};
            bf16x8 k0 = *(const bf16x8*)&Ks[cur][(nt * 16 + l16) * AST + g * 8];
            bf16x8 k1 = *(const bf16x8*)&Ks[cur][(nt * 16 + l16) * AST + 32 + g * 8];
            s[nt] = __builtin_amdgcn_mfma_f32_16x16x32_bf16(qf[0], k0, c16, 0, 0, 0);
            s[nt] = __builtin_amdgcn_mfma_f32_16x16x32_bf16(qf[1], k1, s[nt], 0, 0, 0);
        }

        if (t == qt) {                        // causal mask on diagonal tile
            int j0 = t * 64;
#pragma unroll
            for (int nt = 0; nt < 4; nt++) {
                int key = j0 + nt * 16 + l16;
#pragma unroll
                for (int r = 0; r < 4; r++) {
                    int q = qt * 64 + w * 16 + g * 4 + r;
                    if (key > q) s[nt][r] = -INFINITY;
                }
            }
        }

        // p = exp2(s-16); accumulate per-lane partial l; park p in LDS (trunc bf16:
        // normalization cancels the rounding bias)
#pragma unroll
        for (int nt = 0; nt < 4; nt++)
#pragma unroll
            for (int r = 0; r < 4; r++) {
                float p = exp2f(s[nt][r]);
                lp[r] += p;
                Ps[w][(g * 4 + r) * AST + nt * 16 + l16] = f2bt(p);
            }

        // O += P V
#pragma unroll
        for (int kf = 0; kf < 2; kf++) {
            bf16x8 pf = *(const bf16x8*)&Ps[w][l16 * AST + kf * 32 + g * 8];
#pragma unroll
            for (int nt = 0; nt < 4; nt++) {
                bf16x8 vf = *(const bf16x8*)&Vs[cur][(nt * 16 + l16) * AST + kf * 32 + g * 8];
                o[nt] = __builtin_amdgcn_mfma_f32_16x16x32_bf16(pf, vf, o[nt], 0, 0, 0);
            }
        }
    }

    // single final cross-lane reduction of l (keys were split across 16 lanes)
#pragma unroll
    for (int x = 1; x <= 8; x <<= 1)
#pragma unroll
        for (int r = 0; r < 4; r++)
            lp[r] += __shfl_xor(lp[r], x);

    float inv[4];
#pragma unroll
    for (int r = 0; r < 4; r++) inv[r] = 1.f / lp[r];
    int qg = qt * 64 + w * 16 + g * 4;
#pragma unroll
    for (int nt = 0; nt < 4; nt++)
#pragma unroll
        for (int r = 0; r < 4; r++)
            out[(size_t)(b * T_ + qg + r) * E_ + h * 64 + nt * 16 + l16] =
                f2b(o[nt][r] * inv[r]);
}

extern "C" void kernel_launch(void* const* d_in, const int* in_sizes, int n_in,
                              void* d_out, int out_size, void* d_ws, size_t ws_size,
                              hipStream_t stream) {
    const float* x    = (const float*)d_in[0];
    const float* Wq   = (const float*)d_in[1];
    const float* bq   = (const float*)d_in[2];
    const float* Wk   = (const float*)d_in[3];
    const float* bk   = (const float*)d_in[4];
    const float* Wv   = (const float*)d_in[5];
    const float* bv   = (const float*)d_in[6];
    const float* Wo   = (const float*)d_in[7];
    const float* bo   = (const float*)d_in[8];
    const float* W1   = (const float*)d_in[9];
    const float* b1   = (const float*)d_in[10];
    const float* W2   = (const float*)d_in[11];
    const float* b2   = (const float*)d_in[12];
    const float* ln1g = (const float*)d_in[13];
    const float* ln1b = (const float*)d_in[14];
    const float* ln2g = (const float*)d_in[15];
    const float* ln2b = (const float*)d_in[16];

    char* ws = (char*)d_ws;
    size_t off = 0;
    auto alloc = [&](size_t bytes) { char* p = ws + off; off += (bytes + 255) & ~(size_t)255; return p; };

    u16*   hB    = (u16*)  alloc((size_t)M_ * E_ * 2);        // LN1 out bf16
    u16*   WqkvB = (u16*)  alloc((size_t)3 * E_ * E_ * 2);    // packed q,k,v weights bf16
    u16*   WoB   = (u16*)  alloc((size_t)E_ * E_ * 2);
    u16*   W1B   = (u16*)  alloc((size_t)FF_ * E_ * 2);
    u16*   W2B   = (u16*)  alloc((size_t)E_ * FF_ * 2);
    float* bqkv  = (float*)alloc(3 * E_ * 4);
    u16*   qkB   = (u16*)  alloc((size_t)M_ * 2 * E_ * 2);    // bf16 [M,2048], Q prescaled
    u16*   vtG   = (u16*)  alloc((size_t)M_ * E_ * 2);        // bf16 V^T [B*1024, 2048]
    u16*   attnB = (u16*)  alloc((size_t)M_ * E_ * 2);        // attention out bf16
    float* x2    = (float*)alloc((size_t)M_ * E_ * 4);        // after out-proj + residual
    u16*   h2B   = (u16*)  alloc((size_t)M_ * E_ * 2);        // LN2 out bf16
    u16*   rB    = (u16*)  alloc((size_t)M_ * FF_ * 2);       // relu(ff1) bf16

    // fused weight/bias conversion + LN1 (one launch)
    cvt_ln<<<1024 + 12291, 256, 0, stream>>>(Wq, Wk, Wv, Wo, W1, W2, bq, bk, bv,
                                             WqkvB, WoB, W1B, W2B, bqkv,
                                             x, ln1g, ln1b, hB);

    // fused QKV projection: [4096,1024] x [3072,1024]^T  (768 blocks, 3/CU)
    gemm_bt<128><<<dim3(3 * E_ / 128, M_ / 128), 256, 0, stream>>>(
        hB, WqkvB, bqkv, nullptr, nullptr, qkB, vtG, M_, 3 * E_, E_, 0, 1);

    // flash attention
    attn_mfma<<<B_ * H_ * (T_ / 64), 256, 0, stream>>>(qkB, vtG, attnB);

    // out projection + residual: x2 = x + attn @ Wo^T + bo  (512 blocks, 2/CU)
    gemm_bt<64><<<dim3(E_ / 128, M_ / 64), 256, 0, stream>>>(
        attnB, WoB, bo, x, x2, nullptr, nullptr, M_, E_, E_, 0, 0);

    // LN2
    ln_fwd<<<M_, 64, 0, stream>>>(h2B, x2, ln2g, ln2b);

    // FF1 + relu -> bf16  (1024 blocks, 3/CU at 48KB LDS)
    gemm_bt<128><<<dim3(FF_ / 128, M_ / 128), 256, 0, stream>>>(
        h2B, W1B, b1, nullptr, nullptr, rB, nullptr, M_, FF_, E_, 1, 0);

    // FF2 + residual -> out  (256 blocks = 1/CU, 128x128 tile halves LDS-staged traffic)
    gemm_bt<128><<<dim3(E_ / 128, M_ / 128), 256, 0, stream>>>(
        rB, W2B, b2, x2, (float*)d_out, nullptr, nullptr, M_, E_, FF_, 0, 0);
}

// Round 2
// 387.344 us; speedup vs baseline: 1.0564x; 1.0564x over previous
//
#include <hip/hip_runtime.h>

typedef unsigned short u16;
typedef __bf16 bf16x8 __attribute__((ext_vector_type(8)));
typedef float f32x4 __attribute__((ext_vector_type(4)));

#define E_ 1024
#define T_ 2048
#define B_ 2
#define H_ 16
#define FF_ 4096
#define M_ 4096   // B*T

__device__ __forceinline__ u16 f2b(float f) {
    union { float f; unsigned u; } c; c.f = f;
    unsigned r = c.u + 0x7FFFu + ((c.u >> 16) & 1u);
    return (u16)(r >> 16);
}
// truncating f32->bf16 (1 op); used where downstream normalization cancels bias
__device__ __forceinline__ u16 f2bt(float f) {
    union { float f; unsigned u; } c; c.f = f;
    return (u16)(c.u >> 16);
}

// async global->LDS, 16B per lane; LDS dest = wave-uniform base + lane*16
__device__ __forceinline__ void gl16(const u16* g, u16* l) {
    __builtin_amdgcn_global_load_lds(
        (__attribute__((address_space(1))) void*)g,
        (__attribute__((address_space(3))) void*)l, 16, 0, 0);
}

template<int N> __device__ __forceinline__ void wait_vmcnt() {
    if constexpr (N == 2)      asm volatile("s_waitcnt vmcnt(2)" ::: "memory");
    else if constexpr (N == 3) asm volatile("s_waitcnt vmcnt(3)" ::: "memory");
    else if constexpr (N == 4) asm volatile("s_waitcnt vmcnt(4)" ::: "memory");
    else                       asm volatile("s_waitcnt vmcnt(0)" ::: "memory");
}

// ---------------- fused weight/bias conversion + LN1 ----------------
__global__ __launch_bounds__(256) void cvt_ln(
        const float* __restrict__ Wq, const float* __restrict__ Wk,
        const float* __restrict__ Wv, const float* __restrict__ Wo,
        const float* __restrict__ W1, const float* __restrict__ W2,
        const float* __restrict__ bq, const float* __restrict__ bk,
        const float* __restrict__ bv,
        u16* __restrict__ WqkvB, u16* __restrict__ WoB,
        u16* __restrict__ W1B, u16* __restrict__ W2B,
        float* __restrict__ bqkv,
        const float* __restrict__ x, const float* __restrict__ g1,
        const float* __restrict__ b1v, u16* __restrict__ hB) {
    if (blockIdx.x < 1024) {
        int row = blockIdx.x * 4 + (threadIdx.x >> 6);
        int t = threadIdx.x & 63;
        const float* xr = x + (size_t)row * E_;
        float v[16];
        float sum = 0.f, ss = 0.f;
#pragma unroll
        for (int c = 0; c < 4; c++) {
            float4 f = *(const float4*)&xr[c * 256 + t * 4];
            v[c * 4 + 0] = f.x; v[c * 4 + 1] = f.y; v[c * 4 + 2] = f.z; v[c * 4 + 3] = f.w;
            sum += f.x + f.y + f.z + f.w;
            ss += f.x * f.x + f.y * f.y + f.z * f.z + f.w * f.w;
        }
#pragma unroll
        for (int d = 32; d; d >>= 1) {
            sum += __shfl_xor(sum, d);
            ss  += __shfl_xor(ss, d);
        }
        float mu = sum * (1.f / E_);
        float var = ss * (1.f / E_) - mu * mu;
        float rs = rsqrtf(var + 1e-5f);
#pragma unroll
        for (int c = 0; c < 4; c++) {
            int idx = c * 256 + t * 4;
            float4 g4 = *(const float4*)&g1[idx];
            float4 b4 = *(const float4*)&b1v[idx];
            ushort4 o;
            o.x = f2b((v[c * 4 + 0] - mu) * rs * g4.x + b4.x);
            o.y = f2b((v[c * 4 + 1] - mu) * rs * g4.y + b4.y);
            o.z = f2b((v[c * 4 + 2] - mu) * rs * g4.z + b4.z);
            o.w = f2b((v[c * 4 + 3] - mu) * rs * g4.w + b4.w);
            *(ushort4*)&hB[(size_t)row * E_ + idx] = o;
        }
        return;
    }
    int i = (blockIdx.x - 1024) * 256 + threadIdx.x;
    if (i >= 3146496) return;
    if (i >= 3145728) {             // biases (fp32 copy)
        int j = i - 3145728;        // 0..767
        const float* s = (j < 256) ? bq : (j < 512) ? bk : bv;
        int jj = j & 255;
        *(float4*)&bqkv[j * 4] = *(const float4*)&s[jj * 4];
        return;
    }
    const float* src; u16* dst; int j;
    if (i < 786432) {
        src = (i < 262144) ? Wq : (i < 524288) ? Wk : Wv;
        j = i & 262143;
        dst = WqkvB + (i >> 18) * (E_ * E_);
    } else if (i < 1048576) { j = i - 786432;  src = Wo; dst = WoB; }
    else if (i < 2097152)   { j = i - 1048576; src = W1; dst = W1B; }
    else                    { j = i - 2097152; src = W2; dst = W2B; }
    float4 f = *(const float4*)&src[j * 4];
    ushort4 o;
    o.x = f2b(f.x); o.y = f2b(f.y); o.z = f2b(f.z); o.w = f2b(f.w);
    *(ushort4*)&dst[j * 4] = o;
}

// ---------------- LayerNorm: 1 wave per row of 1024 ----------------
__global__ __launch_bounds__(64) void ln_fwd(u16* __restrict__ out, const float* __restrict__ x,
                                             const float* __restrict__ g, const float* __restrict__ bta) {
    int row = blockIdx.x;
    int t = threadIdx.x;
    const float* xr = x + (size_t)row * E_;
    float v[16];
    float sum = 0.f, ss = 0.f;
#pragma unroll
    for (int c = 0; c < 4; c++) {
        float4 f = *(const float4*)&xr[c * 256 + t * 4];
        v[c * 4 + 0] = f.x; v[c * 4 + 1] = f.y; v[c * 4 + 2] = f.z; v[c * 4 + 3] = f.w;
        sum += f.x + f.y + f.z + f.w;
        ss += f.x * f.x + f.y * f.y + f.z * f.z + f.w * f.w;
    }
#pragma unroll
    for (int d = 32; d; d >>= 1) {
        sum += __shfl_xor(sum, d);
        ss  += __shfl_xor(ss, d);
    }
    float mu = sum * (1.f / E_);
    float var = ss * (1.f / E_) - mu * mu;
    float rs = rsqrtf(var + 1e-5f);
#pragma unroll
    for (int c = 0; c < 4; c++) {
        int idx = c * 256 + t * 4;
        float4 g4 = *(const float4*)&g[idx];
        float4 b4 = *(const float4*)&bta[idx];
        ushort4 o;
        o.x = f2b((v[c * 4 + 0] - mu) * rs * g4.x + b4.x);
        o.y = f2b((v[c * 4 + 1] - mu) * rs * g4.y + b4.y);
        o.z = f2b((v[c * 4 + 2] - mu) * rs * g4.z + b4.z);
        o.w = f2b((v[c * 4 + 3] - mu) * rs * g4.w + b4.w);
        *(ushort4*)&out[(size_t)row * E_ + idx] = o;
    }
}

// ---------------- bf16 MFMA GEMM, 3-stage counted-vmcnt pipeline ----------------
// C[M,N] = A[M,K] * Bt[N,K]^T. BMxBN tile, 256 thr (2x2 waves), BK=32.
// Raw s_barrier + s_waitcnt vmcnt(LA+LB): loads for tiles k+1,k+2 stay in flight
// across the barrier. ldk = row stride (>= K; split-K passes depth K < ldk).
// Split-K mode (outF1 != null): blockIdx.z selects K-chunk; kz0 writes
// acc+bias+residual to outF, kz1 raw acc to outF1; combined by addf4.
template<int BM, int BN>
__global__ __launch_bounds__(256) void gemm_bt(
        const u16* __restrict__ A, const u16* __restrict__ Bt,
        const float* __restrict__ bias, const float* __restrict__ residual,
        float* __restrict__ outF, float* __restrict__ outF1,
        u16* __restrict__ outB, u16* __restrict__ outVt,
        int M, int N, int K, int ldk, int relu, int qkvmode) {
    constexpr int MT = BM / 32, NT = BN / 32;
    constexpr int LA = BM / 64, LB = BN / 64;   // gl16 issues per wave per K-step
    __shared__ __align__(16) u16 As[3][BM * 32];
    __shared__ __align__(16) u16 Bs[3][BN * 32];
    int tid = threadIdx.x;
    int m0 = blockIdx.y * BM, n0 = blockIdx.x * BN;
    int kz = blockIdx.z;
    int koff = kz * K;
    int wave = tid >> 6, lane = tid & 63;
    int wm = wave & 1, wn = wave >> 1;
    int r16 = lane & 15, kg = lane >> 4;

    const u16* gA = A + (size_t)(m0 + wave * (BM / 4) + (lane >> 2)) * ldk + koff + (lane & 3) * 8;
    const u16* gB = Bt + (size_t)(n0 + wave * (BN / 4) + (lane >> 2)) * ldk + koff + (lane & 3) * 8;
    size_t row16 = (size_t)16 * ldk;
    int aoff = wave * (BM / 4) * 32;
    int boff = wave * (BN / 4) * 32;

    f32x4 acc[MT][NT] = {};

    const int nk = K >> 5;              // >= 16 for all call sites

    auto issue = [&](int kt, int buf) {
        int k1 = kt << 5;
        gl16(gA + k1, As[buf] + aoff);
        if (LA == 2) gl16(gA + k1 + row16, As[buf] + aoff + 512);
        gl16(gB + k1, Bs[buf] + boff);
        if (LB == 2) gl16(gB + k1 + row16, Bs[buf] + boff + 512);
    };

    auto compute = [&](int cb) {
        bf16x8 af[MT], bfr[NT];
#pragma unroll
        for (int mt = 0; mt < MT; mt++)
            af[mt] = *(const bf16x8*)&As[cb][(wm * (BM / 2) + mt * 16 + r16) * 32 + kg * 8];
#pragma unroll
        for (int nt = 0; nt < NT; nt++)
            bfr[nt] = *(const bf16x8*)&Bs[cb][(wn * (BN / 2) + nt * 16 + r16) * 32 + kg * 8];
#pragma unroll
        for (int mt = 0; mt < MT; mt++)
#pragma unroll
            for (int nt = 0; nt < NT; nt++)
                acc[mt][nt] = __builtin_amdgcn_mfma_f32_16x16x32_bf16(af[mt], bfr[nt], acc[mt][nt], 0, 0, 0);
    };

    issue(0, 0);
    issue(1, 1);

    int cur = 0;
    for (int ks = 0; ks < nk - 1; ks++) {
        // loads(ks)+loads(ks+1) in flight; wait for ks, keep ks+1 flying.
        wait_vmcnt<LA + LB>();
        __builtin_amdgcn_s_barrier();
        asm volatile("" ::: "memory");
        if (ks + 2 < nk) {
            int p2 = cur ? cur - 1 : 2;     // (cur+2)%3 — buffer read 1 iter ago
            issue(ks + 2, p2);
        }
        compute(cur);
        cur = (cur < 2) ? cur + 1 : 0;
    }
    asm volatile("s_waitcnt vmcnt(0)" ::: "memory");
    __builtin_amdgcn_s_barrier();
    asm volatile("" ::: "memory");
    compute(cur);

#pragma unroll
    for (int mt = 0; mt < MT; mt++) {
#pragma unroll
        for (int nt = 0; nt < NT; nt++) {
            int gm = m0 + wm * (BM / 2) + mt * 16 + kg * 4;
            int gn = n0 + wn * (BN / 2) + nt * 16 + r16;
            float bv = bias[gn];
            if (qkvmode) {
                if (gn < 2048) {
                    // Q prescale: 1/sqrt(64) * log2(e)  (attn softmax runs in exp2 domain)
                    float scl = (gn < 1024) ? 0.18033688f : 1.0f;
#pragma unroll
                    for (int r = 0; r < 4; r++)
                        outB[(size_t)(gm + r) * 2048 + gn] = f2b((acc[mt][nt][r] + bv) * scl);
                } else {
                    int bq_ = gm >> 11, tq = gm & 2047, d = gn - 2048;
                    ushort4 ov;
                    ov.x = f2b(acc[mt][nt][0] + bv);
                    ov.y = f2b(acc[mt][nt][1] + bv);
                    ov.z = f2b(acc[mt][nt][2] + bv);
                    ov.w = f2b(acc[mt][nt][3] + bv);
                    *(ushort4*)&outVt[((size_t)(bq_ * 1024 + d)) * 2048 + tq] = ov;
                }
            } else if (outF1) {              // split-K partials (fp32)
#pragma unroll
                for (int r = 0; r < 4; r++) {
                    size_t off = (size_t)(gm + r) * N + gn;
                    if (kz == 0) {
                        float v = acc[mt][nt][r] + bv;
                        if (residual) v += residual[off];
                        outF[off] = v;
                    } else {
                        outF1[off] = acc[mt][nt][r];
                    }
                }
            } else {
#pragma unroll
                for (int r = 0; r < 4; r++) {
                    float v = acc[mt][nt][r] + bv;
                    size_t off = (size_t)(gm + r) * N + gn;
                    if (residual) v += residual[off];
                    if (relu) v = fmaxf(v, 0.f);
                    if (outF) outF[off] = v;
                    else outB[off] = f2b(v);
                }
            }
        }
    }
}

// split-K combine: d += p  (bias+residual already folded into d by kz0 pass)
__global__ __launch_bounds__(256) void addf4(float* __restrict__ d, const float* __restrict__ p) {
    size_t i = ((size_t)blockIdx.x * 256 + threadIdx.x) * 4;
    float4 a = *(float4*)&d[i];
    float4 b = *(const float4*)&p[i];
    a.x += b.x; a.y += b.y; a.z += b.z; a.w += b.w;
    *(float4*)&d[i] = a;
}

// ---------------- MFMA flash attention (bf16, causal, FIXED-SHIFT exp2 softmax) -----
// softmax is shift-invariant; scores in log2 domain have std~0.5, max<<16 (LN'd
// inputs x uniform(1/32) weights). Fixed shift c=16 (folded into MFMA C-init)
// removes ALL online-softmax bookkeeping: no max tree, no sum tree, no rescale.
// l = per-lane partial, reduced once at the end. Overflow would need s>143.
#define AST 68   // 34 dw stride: bank-conflict-free for all access patterns here
__global__ __launch_bounds__(256) void attn_mfma(
        const u16* __restrict__ qk, const u16* __restrict__ vt,
        u16* __restrict__ out) {
    __shared__ __align__(16) u16 Ks[2][64 * AST];  // K[key][d]
    __shared__ __align__(16) u16 Vs[2][64 * AST];  // Vt[d][key]
    __shared__ __align__(16) u16 Ps[4][16 * AST];  // per-wave P[q][key]

    int bz = blockIdx.x;
    int h  = bz & 15;
    int b  = (bz >> 4) & 1;
    int qt = bz >> 5;

    int tid = threadIdx.x;
    int w = tid >> 6, lane = tid & 63;
    int g = lane >> 4, l16 = lane & 15;

    int qrow = qt * 64 + w * 16 + l16;
    bf16x8 qf[2];
    qf[0] = *(const bf16x8*)&qk[(size_t)(b * T_ + qrow) * 2048 + h * 64 + g * 8];
    qf[1] = *(const bf16x8*)&qk[(size_t)(b * T_ + qrow) * 2048 + h * 64 + 32 + g * 8];

    f32x4 o[4] = {};
    f32x4 lp = {0.f, 0.f, 0.f, 0.f};      // per-lane partial row-sums (index r)

    int r1 = tid >> 3, col1 = (tid & 7) * 8;
    const u16* gK = qk + (size_t)(b * T_) * 2048 + 1024 + h * 64;
    const u16* gV = vt + (size_t)(b * 1024 + h * 64) * 2048;

    uint4 kr1 = *(const uint4*)&gK[(size_t)r1 * 2048 + col1];
    uint4 kr2 = *(const uint4*)&gK[(size_t)(r1 + 32) * 2048 + col1];
    uint4 vr1 = *(const uint4*)&gV[(size_t)r1 * 2048 + col1];
    uint4 vr2 = *(const uint4*)&gV[(size_t)(r1 + 32) * 2048 + col1];

    for (int t = 0; t <= qt; t++) {
        int cur = t & 1;
        *(uint4*)&Ks[cur][r1 * AST + col1] = kr1;
        *(uint4*)&Ks[cur][(r1 + 32) * AST + col1] = kr2;
        *(uint4*)&Vs[cur][r1 * AST + col1] = vr1;
        *(uint4*)&Vs[cur][(r1 + 32) * AST + col1] = vr2;
        __syncthreads();                      // single barrier per tile
        if (t < qt) {                         // issue next-tile loads AFTER barrier
            int j1 = (t + 1) * 64;
            kr1 = *(const uint4*)&gK[(size_t)(j1 + r1) * 2048 + col1];
            kr2 = *(const uint4*)&gK[(size_t)(j1 + r1 + 32) * 2048 + col1];
            vr1 = *(const uint4*)&gV[(size_t)r1 * 2048 + j1 + col1];
            vr2 = *(const uint4*)&gV[(size_t)(r1 + 32) * 2048 + j1 + col1];
        }

        // S - 16 = Q K^T + C(-16)  (C-layout: key = nt*16+l16, q = g*4+r)
        f32x4 s[4];
#pragma unroll
        for (int nt = 0; nt < 4; nt++) {
            f32x4 c16 = {-16.f, -16.f, -16.f, -16.f};
            bf16x8 k0 = *(const bf16x8*)&Ks[cur][(nt * 16 + l16) * AST + g * 8];
            bf16x8 k1 = *(const bf16x8*)&Ks[cur][(nt * 16 + l16) * AST + 32 + g * 8];
            s[nt] = __builtin_amdgcn_mfma_f32_16x16x32_bf16(qf[0], k0, c16, 0, 0, 0);
            s[nt] = __builtin_amdgcn_mfma_f32_16x16x32_bf16(qf[1], k1, s[nt], 0, 0, 0);
        }

        if (t == qt) {                        // causal mask on diagonal tile
            int j0 = t * 64;
#pragma unroll
            for (int nt = 0; nt < 4; nt++) {
                int key = j0 + nt * 16 + l16;
#pragma unroll
                for (int r = 0; r < 4; r++) {
                    int q = qt * 64 + w * 16 + g * 4 + r;
                    if (key > q) s[nt][r] = -INFINITY;
                }
            }
        }

        // p = exp2(s-16); accumulate per-lane partial l; park p in LDS (trunc bf16:
        // normalization cancels the rounding bias)
#pragma unroll
        for (int nt = 0; nt < 4; nt++)
#pragma unroll
            for (int r = 0; r < 4; r++) {
                float p = exp2f(s[nt][r]);
                lp[r] += p;
                Ps[w][(g * 4 + r) * AST + nt * 16 + l16] = f2bt(p);
            }

        // O += P V
#pragma unroll
        for (int kf = 0; kf < 2; kf++) {
            bf16x8 pf = *(const bf16x8*)&Ps[w][l16 * AST + kf * 32 + g * 8];
#pragma unroll
            for (int nt = 0; nt < 4; nt++) {
                bf16x8 vf = *(const bf16x8*)&Vs[cur][(nt * 16 + l16) * AST + kf * 32 + g * 8];
                o[nt] = __builtin_amdgcn_mfma_f32_16x16x32_bf16(pf, vf, o[nt], 0, 0, 0);
            }
        }
    }

    // single final cross-lane reduction of l (keys were split across 16 lanes)
#pragma unroll
    for (int x = 1; x <= 8; x <<= 1)
#pragma unroll
        for (int r = 0; r < 4; r++)
            lp[r] += __shfl_xor(lp[r], x);

    float inv[4];
#pragma unroll
    for (int r = 0; r < 4; r++) inv[r] = 1.f / lp[r];
    int qg = qt * 64 + w * 16 + g * 4;
#pragma unroll
    for (int nt = 0; nt < 4; nt++)
#pragma unroll
        for (int r = 0; r < 4; r++)
            out[(size_t)(b * T_ + qg + r) * E_ + h * 64 + nt * 16 + l16] =
                f2b(o[nt][r] * inv[r]);
}

extern "C" void kernel_launch(void* const* d_in, const int* in_sizes, int n_in,
                              void* d_out, int out_size, void* d_ws, size_t ws_size,
                              hipStream_t stream) {
    const float* x    = (const float*)d_in[0];
    const float* Wq   = (const float*)d_in[1];
    const float* bq   = (const float*)d_in[2];
    const float* Wk   = (const float*)d_in[3];
    const float* bk   = (const float*)d_in[4];
    const float* Wv   = (const float*)d_in[5];
    const float* bv   = (const float*)d_in[6];
    const float* Wo   = (const float*)d_in[7];
    const float* bo   = (const float*)d_in[8];
    const float* W1   = (const float*)d_in[9];
    const float* b1   = (const float*)d_in[10];
    const float* W2   = (const float*)d_in[11];
    const float* b2   = (const float*)d_in[12];
    const float* ln1g = (const float*)d_in[13];
    const float* ln1b = (const float*)d_in[14];
    const float* ln2g = (const float*)d_in[15];
    const float* ln2b = (const float*)d_in[16];

    char* ws = (char*)d_ws;
    size_t off = 0;
    auto alloc = [&](size_t bytes) { char* p = ws + off; off += (bytes + 255) & ~(size_t)255; return p; };

    u16*   hB    = (u16*)  alloc((size_t)M_ * E_ * 2);        // LN1 out bf16
    u16*   WqkvB = (u16*)  alloc((size_t)3 * E_ * E_ * 2);    // packed q,k,v weights bf16
    u16*   WoB   = (u16*)  alloc((size_t)E_ * E_ * 2);
    u16*   W1B   = (u16*)  alloc((size_t)FF_ * E_ * 2);
    u16*   W2B   = (u16*)  alloc((size_t)E_ * FF_ * 2);
    float* bqkv  = (float*)alloc(3 * E_ * 4);
    u16*   qkB   = (u16*)  alloc((size_t)M_ * 2 * E_ * 2);    // bf16 [M,2048], Q prescaled
    u16*   vtG   = (u16*)  alloc((size_t)M_ * E_ * 2);        // bf16 V^T [B*1024, 2048]
    u16*   attnB = (u16*)  alloc((size_t)M_ * E_ * 2);        // attention out bf16
    float* x2    = (float*)alloc((size_t)M_ * E_ * 4);        // after out-proj + residual
    u16*   h2B   = (u16*)  alloc((size_t)M_ * E_ * 2);        // LN2 out bf16
    u16*   rB    = (u16*)  alloc((size_t)M_ * FF_ * 2);       // relu(ff1) bf16
    float* P1    = (float*)alloc((size_t)M_ * E_ * 4);        // FF2 split-K partial (kz=1)

    // fused weight/bias conversion + LN1 (one launch)
    cvt_ln<<<1024 + 12291, 256, 0, stream>>>(Wq, Wk, Wv, Wo, W1, W2, bq, bk, bv,
                                             WqkvB, WoB, W1B, W2B, bqkv,
                                             x, ln1g, ln1b, hB);

    // fused QKV projection: [4096,1024] x [3072,1024]^T  (768 blocks, 3/CU)
    gemm_bt<128, 128><<<dim3(3 * E_ / 128, M_ / 128), 256, 0, stream>>>(
        hB, WqkvB, bqkv, nullptr, nullptr, nullptr, qkB, vtG, M_, 3 * E_, E_, E_, 0, 1);

    // flash attention
    attn_mfma<<<B_ * H_ * (T_ / 64), 256, 0, stream>>>(qkB, vtG, attnB);

    // out projection + residual: x2 = x + attn @ Wo^T + bo  (512 blocks, 2/CU)
    gemm_bt<64, 128><<<dim3(E_ / 128, M_ / 64), 256, 0, stream>>>(
        attnB, WoB, bo, x, x2, nullptr, nullptr, nullptr, M_, E_, E_, E_, 0, 0);

    // LN2
    ln_fwd<<<M_, 64, 0, stream>>>(h2B, x2, ln2g, ln2b);

    // FF1 + relu -> bf16  (1024 blocks, 3/CU at 48KB LDS)
    gemm_bt<128, 128><<<dim3(FF_ / 128, M_ / 128), 256, 0, stream>>>(
        h2B, W1B, b1, nullptr, nullptr, nullptr, rB, nullptr, M_, FF_, E_, E_, 1, 0);

    // FF2 split-K=2: grid (8,64,2) = 1024 blocks = 4/CU, K=2048 each (ldk=4096).
    // kz0 -> d_out (acc+bias+residual), kz1 -> P1 (raw acc)
    gemm_bt<64, 128><<<dim3(E_ / 128, M_ / 64, 2), 256, 0, stream>>>(
        rB, W2B, b2, x2, (float*)d_out, P1, nullptr, nullptr, M_, E_, FF_ / 2, FF_, 0, 0);

    // combine: d_out += P1  (16MB fp32, float4 grid-stride-free exact cover)
    addf4<<<(M_ * E_) / (256 * 4), 256, 0, stream>>>((float*)d_out, P1);
}

// Round 3
// 385.176 us; speedup vs baseline: 1.0623x; 1.0056x over previous
//
#include <hip/hip_runtime.h>

typedef unsigned short u16;
typedef __bf16 bf16x8 __attribute__((ext_vector_type(8)));
typedef float f32x4 __attribute__((ext_vector_type(4)));

#define E_ 1024
#define T_ 2048
#define B_ 2
#define H_ 16
#define FF_ 4096
#define M_ 4096   // B*T

__device__ __forceinline__ u16 f2b(float f) {
    union { float f; unsigned u; } c; c.f = f;
    unsigned r = c.u + 0x7FFFu + ((c.u >> 16) & 1u);
    return (u16)(r >> 16);
}
// truncating f32->bf16 (1 op); used where downstream normalization cancels bias
__device__ __forceinline__ u16 f2bt(float f) {
    union { float f; unsigned u; } c; c.f = f;
    return (u16)(c.u >> 16);
}

// async global->LDS, 16B per lane; LDS dest = wave-uniform base + lane*16
__device__ __forceinline__ void gl16(const u16* g, u16* l) {
    __builtin_amdgcn_global_load_lds(
        (__attribute__((address_space(1))) void*)g,
        (__attribute__((address_space(3))) void*)l, 16, 0, 0);
}

template<int N> __device__ __forceinline__ void wait_vmcnt() {
    if constexpr (N == 2)      asm volatile("s_waitcnt vmcnt(2)" ::: "memory");
    else if constexpr (N == 3) asm volatile("s_waitcnt vmcnt(3)" ::: "memory");
    else if constexpr (N == 4) asm volatile("s_waitcnt vmcnt(4)" ::: "memory");
    else                       asm volatile("s_waitcnt vmcnt(0)" ::: "memory");
}

// ---------------- fused weight/bias conversion + LN1 ----------------
__global__ __launch_bounds__(256) void cvt_ln(
        const float* __restrict__ Wq, const float* __restrict__ Wk,
        const float* __restrict__ Wv, const float* __restrict__ Wo,
        const float* __restrict__ W1, const float* __restrict__ W2,
        const float* __restrict__ bq, const float* __restrict__ bk,
        const float* __restrict__ bv,
        u16* __restrict__ WqkvB, u16* __restrict__ WoB,
        u16* __restrict__ W1B, u16* __restrict__ W2B,
        float* __restrict__ bqkv,
        const float* __restrict__ x, const float* __restrict__ g1,
        const float* __restrict__ b1v, u16* __restrict__ hB) {
    if (blockIdx.x < 1024) {
        int row = blockIdx.x * 4 + (threadIdx.x >> 6);
        int t = threadIdx.x & 63;
        const float* xr = x + (size_t)row * E_;
        float v[16];
        float sum = 0.f, ss = 0.f;
#pragma unroll
        for (int c = 0; c < 4; c++) {
            float4 f = *(const float4*)&xr[c * 256 + t * 4];
            v[c * 4 + 0] = f.x; v[c * 4 + 1] = f.y; v[c * 4 + 2] = f.z; v[c * 4 + 3] = f.w;
            sum += f.x + f.y + f.z + f.w;
            ss += f.x * f.x + f.y * f.y + f.z * f.z + f.w * f.w;
        }
#pragma unroll
        for (int d = 32; d; d >>= 1) {
            sum += __shfl_xor(sum, d);
            ss  += __shfl_xor(ss, d);
        }
        float mu = sum * (1.f / E_);
        float var = ss * (1.f / E_) - mu * mu;
        float rs = rsqrtf(var + 1e-5f);
#pragma unroll
        for (int c = 0; c < 4; c++) {
            int idx = c * 256 + t * 4;
            float4 g4 = *(const float4*)&g1[idx];
            float4 b4 = *(const float4*)&b1v[idx];
            ushort4 o;
            o.x = f2b((v[c * 4 + 0] - mu) * rs * g4.x + b4.x);
            o.y = f2b((v[c * 4 + 1] - mu) * rs * g4.y + b4.y);
            o.z = f2b((v[c * 4 + 2] - mu) * rs * g4.z + b4.z);
            o.w = f2b((v[c * 4 + 3] - mu) * rs * g4.w + b4.w);
            *(ushort4*)&hB[(size_t)row * E_ + idx] = o;
        }
        return;
    }
    int i = (blockIdx.x - 1024) * 256 + threadIdx.x;
    if (i >= 3146496) return;
    if (i >= 3145728) {             // biases (fp32 copy)
        int j = i - 3145728;        // 0..767
        const float* s = (j < 256) ? bq : (j < 512) ? bk : bv;
        int jj = j & 255;
        *(float4*)&bqkv[j * 4] = *(const float4*)&s[jj * 4];
        return;
    }
    const float* src; u16* dst; int j;
    if (i < 786432) {
        src = (i < 262144) ? Wq : (i < 524288) ? Wk : Wv;
        j = i & 262143;
        dst = WqkvB + (i >> 18) * (E_ * E_);
    } else if (i < 1048576) { j = i - 786432;  src = Wo; dst = WoB; }
    else if (i < 2097152)   { j = i - 1048576; src = W1; dst = W1B; }
    else                    { j = i - 2097152; src = W2; dst = W2B; }
    float4 f = *(const float4*)&src[j * 4];
    ushort4 o;
    o.x = f2b(f.x); o.y = f2b(f.y); o.z = f2b(f.z); o.w = f2b(f.w);
    *(ushort4*)&dst[j * 4] = o;
}

// ---------------- LayerNorm: 1 wave per row of 1024 ----------------
__global__ __launch_bounds__(64) void ln_fwd(u16* __restrict__ out, const float* __restrict__ x,
                                             const float* __restrict__ g, const float* __restrict__ bta) {
    int row = blockIdx.x;
    int t = threadIdx.x;
    const float* xr = x + (size_t)row * E_;
    float v[16];
    float sum = 0.f, ss = 0.f;
#pragma unroll
    for (int c = 0; c < 4; c++) {
        float4 f = *(const float4*)&xr[c * 256 + t * 4];
        v[c * 4 + 0] = f.x; v[c * 4 + 1] = f.y; v[c * 4 + 2] = f.z; v[c * 4 + 3] = f.w;
        sum += f.x + f.y + f.z + f.w;
        ss += f.x * f.x + f.y * f.y + f.z * f.z + f.w * f.w;
    }
#pragma unroll
    for (int d = 32; d; d >>= 1) {
        sum += __shfl_xor(sum, d);
        ss  += __shfl_xor(ss, d);
    }
    float mu = sum * (1.f / E_);
    float var = ss * (1.f / E_) - mu * mu;
    float rs = rsqrtf(var + 1e-5f);
#pragma unroll
    for (int c = 0; c < 4; c++) {
        int idx = c * 256 + t * 4;
        float4 g4 = *(const float4*)&g[idx];
        float4 b4 = *(const float4*)&bta[idx];
        ushort4 o;
        o.x = f2b((v[c * 4 + 0] - mu) * rs * g4.x + b4.x);
        o.y = f2b((v[c * 4 + 1] - mu) * rs * g4.y + b4.y);
        o.z = f2b((v[c * 4 + 2] - mu) * rs * g4.z + b4.z);
        o.w = f2b((v[c * 4 + 3] - mu) * rs * g4.w + b4.w);
        *(ushort4*)&out[(size_t)row * E_ + idx] = o;
    }
}

// ---------------- bf16 MFMA GEMM, 3-stage counted-vmcnt pipeline ----------------
// C[M,N] = A[M,K] * Bt[N,K]^T. BMxBN tile, 256 thr (2x2 waves, 64x64 per wave at
// BM=BN=128: 8 ds_read_b128 per 16 MFMA). BK=32.
// Raw s_barrier + s_waitcnt vmcnt(LA+LB): loads for tiles k+1,k+2 stay in flight
// across the barrier. ldk = row stride (>= K; split-K passes depth K < ldk).
// Split-K (oP1 != null): kz0 -> outF (acc+bias+residual); kz>=1 -> raw acc into
// oP1/oP2/oP3. swz: XCD-chunked blockIdx remap (T1) for per-XCD L2 reuse.
template<int BM, int BN>
__global__ __launch_bounds__(256) void gemm_bt(
        const u16* __restrict__ A, const u16* __restrict__ Bt,
        const float* __restrict__ bias, const float* __restrict__ residual,
        float* __restrict__ outF, float* __restrict__ oP1,
        float* __restrict__ oP2, float* __restrict__ oP3,
        u16* __restrict__ outB, u16* __restrict__ outVt,
        int M, int N, int K, int ldk, int relu, int qkvmode, int swz) {
    constexpr int MT = BM / 32, NT = BN / 32;
    constexpr int LA = BM / 64, LB = BN / 64;   // gl16 issues per wave per K-step
    __shared__ __align__(16) u16 As[3][BM * 32];
    __shared__ __align__(16) u16 Bs[3][BN * 32];
    int tid = threadIdx.x;
    int bx = blockIdx.x, by = blockIdx.y;
    if (swz) {   // per-kz-plane chunked swizzle: XCD i gets contiguous chunk i
        int gx = gridDim.x;
        int nwg = gx * gridDim.y;          // all call sites: nwg % 8 == 0
        int lin = by * gx + bx;
        int w = (lin & 7) * (nwg >> 3) + (lin >> 3);
        bx = w % gx; by = w / gx;
    }
    int m0 = by * BM, n0 = bx * BN;
    int kz = blockIdx.z;
    int koff = kz * K;
    int wave = tid >> 6, lane = tid & 63;
    int wm = wave & 1, wn = wave >> 1;
    int r16 = lane & 15, kg = lane >> 4;

    const u16* gA = A + (size_t)(m0 + wave * (BM / 4) + (lane >> 2)) * ldk + koff + (lane & 3) * 8;
    const u16* gB = Bt + (size_t)(n0 + wave * (BN / 4) + (lane >> 2)) * ldk + koff + (lane & 3) * 8;
    size_t row16 = (size_t)16 * ldk;
    int aoff = wave * (BM / 4) * 32;
    int boff = wave * (BN / 4) * 32;

    f32x4 acc[MT][NT] = {};

    const int nk = K >> 5;              // >= 16 for all call sites

    auto issue = [&](int kt, int buf) {
        int k1 = kt << 5;
        gl16(gA + k1, As[buf] + aoff);
        if (LA == 2) gl16(gA + k1 + row16, As[buf] + aoff + 512);
        gl16(gB + k1, Bs[buf] + boff);
        if (LB == 2) gl16(gB + k1 + row16, Bs[buf] + boff + 512);
    };

    auto compute = [&](int cb) {
        bf16x8 af[MT], bfr[NT];
#pragma unroll
        for (int mt = 0; mt < MT; mt++)
            af[mt] = *(const bf16x8*)&As[cb][(wm * (BM / 2) + mt * 16 + r16) * 32 + kg * 8];
#pragma unroll
        for (int nt = 0; nt < NT; nt++)
            bfr[nt] = *(const bf16x8*)&Bs[cb][(wn * (BN / 2) + nt * 16 + r16) * 32 + kg * 8];
#pragma unroll
        for (int mt = 0; mt < MT; mt++)
#pragma unroll
            for (int nt = 0; nt < NT; nt++)
                acc[mt][nt] = __builtin_amdgcn_mfma_f32_16x16x32_bf16(af[mt], bfr[nt], acc[mt][nt], 0, 0, 0);
    };

    issue(0, 0);
    issue(1, 1);

    int cur = 0;
    for (int ks = 0; ks < nk - 1; ks++) {
        // loads(ks)+loads(ks+1) in flight; wait for ks, keep ks+1 flying.
        wait_vmcnt<LA + LB>();
        __builtin_amdgcn_s_barrier();
        asm volatile("" ::: "memory");
        if (ks + 2 < nk) {
            int p2 = cur ? cur - 1 : 2;     // (cur+2)%3 — buffer read 1 iter ago
            issue(ks + 2, p2);
        }
        compute(cur);
        cur = (cur < 2) ? cur + 1 : 0;
    }
    asm volatile("s_waitcnt vmcnt(0)" ::: "memory");
    __builtin_amdgcn_s_barrier();
    asm volatile("" ::: "memory");
    compute(cur);

#pragma unroll
    for (int mt = 0; mt < MT; mt++) {
#pragma unroll
        for (int nt = 0; nt < NT; nt++) {
            int gm = m0 + wm * (BM / 2) + mt * 16 + kg * 4;
            int gn = n0 + wn * (BN / 2) + nt * 16 + r16;
            float bv = bias[gn];
            if (qkvmode) {
                if (gn < 2048) {
                    // Q prescale: 1/sqrt(64) * log2(e)  (attn softmax runs in exp2 domain)
                    float scl = (gn < 1024) ? 0.18033688f : 1.0f;
#pragma unroll
                    for (int r = 0; r < 4; r++)
                        outB[(size_t)(gm + r) * 2048 + gn] = f2b((acc[mt][nt][r] + bv) * scl);
                } else {
                    int bq_ = gm >> 11, tq = gm & 2047, d = gn - 2048;
                    ushort4 ov;
                    ov.x = f2b(acc[mt][nt][0] + bv);
                    ov.y = f2b(acc[mt][nt][1] + bv);
                    ov.z = f2b(acc[mt][nt][2] + bv);
                    ov.w = f2b(acc[mt][nt][3] + bv);
                    *(ushort4*)&outVt[((size_t)(bq_ * 1024 + d)) * 2048 + tq] = ov;
                }
            } else if (oP1) {                // split-K partials (fp32)
                float* po = (kz == 1) ? oP1 : (kz == 2) ? oP2 : oP3;
#pragma unroll
                for (int r = 0; r < 4; r++) {
                    size_t off = (size_t)(gm + r) * N + gn;
                    if (kz == 0) {
                        float v = acc[mt][nt][r] + bv;
                        if (residual) v += residual[off];
                        outF[off] = v;
                    } else {
                        po[off] = acc[mt][nt][r];
                    }
                }
            } else {
#pragma unroll
                for (int r = 0; r < 4; r++) {
                    float v = acc[mt][nt][r] + bv;
                    size_t off = (size_t)(gm + r) * N + gn;
                    if (residual) v += residual[off];
                    if (relu) v = fmaxf(v, 0.f);
                    if (outF) outF[off] = v;
                    else outB[off] = f2b(v);
                }
            }
        }
    }
}

// split-K combine: d += a + b + c  (bias+residual already folded into d by kz0 pass)
__global__ __launch_bounds__(256) void addf3(float* __restrict__ d, const float* __restrict__ a,
                                             const float* __restrict__ b, const float* __restrict__ c) {
    size_t i = ((size_t)blockIdx.x * 256 + threadIdx.x) * 4;
    float4 vd = *(float4*)&d[i];
    float4 va = *(const float4*)&a[i];
    float4 vb = *(const float4*)&b[i];
    float4 vc = *(const float4*)&c[i];
    vd.x += va.x + vb.x + vc.x;
    vd.y += va.y + vb.y + vc.y;
    vd.z += va.z + vb.z + vc.z;
    vd.w += va.w + vb.w + vc.w;
    *(float4*)&d[i] = vd;
}

// ---------------- MFMA flash attention (bf16, causal, FIXED-SHIFT exp2 softmax) -----
// softmax is shift-invariant; scores in log2 domain have std~0.5, max<<16 (LN'd
// inputs x uniform(1/32) weights). Fixed shift c=16 (folded into MFMA C-init)
// removes ALL online-softmax bookkeeping: no max tree, no sum tree, no rescale.
// l = per-lane partial, reduced once at the end. Overflow would need s>143.
#define AST 68   // 34 dw stride: bank-conflict-free for all access patterns here
__global__ __launch_bounds__(256) void attn_mfma(
        const u16* __restrict__ qk, const u16* __restrict__ vt,
        u16* __restrict__ out) {
    __shared__ __align__(16) u16 Ks[2][64 * AST];  // K[key][d]
    __shared__ __align__(16) u16 Vs[2][64 * AST];  // Vt[d][key]
    __shared__ __align__(16) u16 Ps[4][16 * AST];  // per-wave P[q][key]

    int bz = blockIdx.x;
    int h  = bz & 15;
    int b  = (bz >> 4) & 1;
    int qt = bz >> 5;

    int tid = threadIdx.x;
    int w = tid >> 6, lane = tid & 63;
    int g = lane >> 4, l16 = lane & 15;

    int qrow = qt * 64 + w * 16 + l16;
    bf16x8 qf[2];
    qf[0] = *(const bf16x8*)&qk[(size_t)(b * T_ + qrow) * 2048 + h * 64 + g * 8];
    qf[1] = *(const bf16x8*)&qk[(size_t)(b * T_ + qrow) * 2048 + h * 64 + 32 + g * 8];

    f32x4 o[4] = {};
    f32x4 lp = {0.f, 0.f, 0.f, 0.f};      // per-lane partial row-sums (index r)

    int r1 = tid >> 3, col1 = (tid & 7) * 8;
    const u16* gK = qk + (size_t)(b * T_) * 2048 + 1024 + h * 64;
    const u16* gV = vt + (size_t)(b * 1024 + h * 64) * 2048;

    uint4 kr1 = *(const uint4*)&gK[(size_t)r1 * 2048 + col1];
    uint4 kr2 = *(const uint4*)&gK[(size_t)(r1 + 32) * 2048 + col1];
    uint4 vr1 = *(const uint4*)&gV[(size_t)r1 * 2048 + col1];
    uint4 vr2 = *(const uint4*)&gV[(size_t)(r1 + 32) * 2048 + col1];

    for (int t = 0; t <= qt; t++) {
        int cur = t & 1;
        *(uint4*)&Ks[cur][r1 * AST + col1] = kr1;
        *(uint4*)&Ks[cur][(r1 + 32) * AST + col1] = kr2;
        *(uint4*)&Vs[cur][r1 * AST + col1] = vr1;
        *(uint4*)&Vs[cur][(r1 + 32) * AST + col1] = vr2;
        __syncthreads();                      // single barrier per tile
        if (t < qt) {                         // issue next-tile loads AFTER barrier
            int j1 = (t + 1) * 64;
            kr1 = *(const uint4*)&gK[(size_t)(j1 + r1) * 2048 + col1];
            kr2 = *(const uint4*)&gK[(size_t)(j1 + r1 + 32) * 2048 + col1];
            vr1 = *(const uint4*)&gV[(size_t)r1 * 2048 + j1 + col1];
            vr2 = *(const uint4*)&gV[(size_t)(r1 + 32) * 2048 + j1 + col1];
        }

        // S - 16 = Q K^T + C(-16)  (C-layout: key = nt*16+l16, q = g*4+r)
        f32x4 s[4];
#pragma unroll
        for (int nt = 0; nt < 4; nt++) {
            f32x4 c16 = {-16.f, -16.f, -16.f, -16.f};
            bf16x8 k0 = *(const bf16x8*)&Ks[cur][(nt * 16 + l16) * AST + g * 8];
            bf16x8 k1 = *(const bf16x8*)&Ks[cur][(nt * 16 + l16) * AST + 32 + g * 8];
            s[nt] = __builtin_amdgcn_mfma_f32_16x16x32_bf16(qf[0], k0, c16, 0, 0, 0);
            s[nt] = __builtin_amdgcn_mfma_f32_16x16x32_bf16(qf[1], k1, s[nt], 0, 0, 0);
        }

        if (t == qt) {                        // causal mask on diagonal tile
            int j0 = t * 64;
#pragma unroll
            for (int nt = 0; nt < 4; nt++) {
                int key = j0 + nt * 16 + l16;
#pragma unroll
                for (int r = 0; r < 4; r++) {
                    int q = qt * 64 + w * 16 + g * 4 + r;
                    if (key > q) s[nt][r] = -INFINITY;
                }
            }
        }

        // p = exp2(s-16); accumulate per-lane partial l; park p in LDS (trunc bf16:
        // normalization cancels the rounding bias)
#pragma unroll
        for (int nt = 0; nt < 4; nt++)
#pragma unroll
            for (int r = 0; r < 4; r++) {
                float p = exp2f(s[nt][r]);
                lp[r] += p;
                Ps[w][(g * 4 + r) * AST + nt * 16 + l16] = f2bt(p);
            }

        // O += P V
#pragma unroll
        for (int kf = 0; kf < 2; kf++) {
            bf16x8 pf = *(const bf16x8*)&Ps[w][l16 * AST + kf * 32 + g * 8];
#pragma unroll
            for (int nt = 0; nt < 4; nt++) {
                bf16x8 vf = *(const bf16x8*)&Vs[cur][(nt * 16 + l16) * AST + kf * 32 + g * 8];
                o[nt] = __builtin_amdgcn_mfma_f32_16x16x32_bf16(pf, vf, o[nt], 0, 0, 0);
            }
        }
    }

    // single final cross-lane reduction of l (keys were split across 16 lanes)
#pragma unroll
    for (int x = 1; x <= 8; x <<= 1)
#pragma unroll
        for (int r = 0; r < 4; r++)
            lp[r] += __shfl_xor(lp[r], x);

    float inv[4];
#pragma unroll
    for (int r = 0; r < 4; r++) inv[r] = 1.f / lp[r];
    int qg = qt * 64 + w * 16 + g * 4;
#pragma unroll
    for (int nt = 0; nt < 4; nt++)
#pragma unroll
        for (int r = 0; r < 4; r++)
            out[(size_t)(b * T_ + qg + r) * E_ + h * 64 + nt * 16 + l16] =
                f2b(o[nt][r] * inv[r]);
}

extern "C" void kernel_launch(void* const* d_in, const int* in_sizes, int n_in,
                              void* d_out, int out_size, void* d_ws, size_t ws_size,
                              hipStream_t stream) {
    const float* x    = (const float*)d_in[0];
    const float* Wq   = (const float*)d_in[1];
    const float* bq   = (const float*)d_in[2];
    const float* Wk   = (const float*)d_in[3];
    const float* bk   = (const float*)d_in[4];
    const float* Wv   = (const float*)d_in[5];
    const float* bv   = (const float*)d_in[6];
    const float* Wo   = (const float*)d_in[7];
    const float* bo   = (const float*)d_in[8];
    const float* W1   = (const float*)d_in[9];
    const float* b1   = (const float*)d_in[10];
    const float* W2   = (const float*)d_in[11];
    const float* b2   = (const float*)d_in[12];
    const float* ln1g = (const float*)d_in[13];
    const float* ln1b = (const float*)d_in[14];
    const float* ln2g = (const float*)d_in[15];
    const float* ln2b = (const float*)d_in[16];

    char* ws = (char*)d_ws;
    size_t off = 0;
    auto alloc = [&](size_t bytes) { char* p = ws + off; off += (bytes + 255) & ~(size_t)255; return p; };

    u16*   hB    = (u16*)  alloc((size_t)M_ * E_ * 2);        // LN1 out bf16
    u16*   WqkvB = (u16*)  alloc((size_t)3 * E_ * E_ * 2);    // packed q,k,v weights bf16
    u16*   WoB   = (u16*)  alloc((size_t)E_ * E_ * 2);
    u16*   W1B   = (u16*)  alloc((size_t)FF_ * E_ * 2);
    u16*   W2B   = (u16*)  alloc((size_t)E_ * FF_ * 2);
    float* bqkv  = (float*)alloc(3 * E_ * 4);
    u16*   qkB   = (u16*)  alloc((size_t)M_ * 2 * E_ * 2);    // bf16 [M,2048], Q prescaled
    u16*   vtG   = (u16*)  alloc((size_t)M_ * E_ * 2);        // bf16 V^T [B*1024, 2048]
    u16*   attnB = (u16*)  alloc((size_t)M_ * E_ * 2);        // attention out bf16
    float* x2    = (float*)alloc((size_t)M_ * E_ * 4);        // after out-proj + residual
    u16*   h2B   = (u16*)  alloc((size_t)M_ * E_ * 2);        // LN2 out bf16
    u16*   rB    = (u16*)  alloc((size_t)M_ * FF_ * 2);       // relu(ff1) bf16
    float* P1    = (float*)alloc((size_t)M_ * E_ * 4);        // FF2 split-K partial (kz=1)
    // kz=2,3 partials alias workspace that is dead by FF2 time:
    float* P2 = (float*)qkB;    // 16 MB, dead after attn
    float* P3 = (float*)ws;     // hB+WqkvB+WoB = 8+6+2 = 16 MB, dead after Wo-proj

    // fused weight/bias conversion + LN1 (one launch)
    cvt_ln<<<1024 + 12291, 256, 0, stream>>>(Wq, Wk, Wv, Wo, W1, W2, bq, bk, bv,
                                             WqkvB, WoB, W1B, W2B, bqkv,
                                             x, ln1g, ln1b, hB);

    // fused QKV projection: [4096,1024] x [3072,1024]^T  (768 blocks, 3/CU)
    gemm_bt<128, 128><<<dim3(3 * E_ / 128, M_ / 128), 256, 0, stream>>>(
        hB, WqkvB, bqkv, nullptr, nullptr, nullptr, nullptr, nullptr, qkB, vtG,
        M_, 3 * E_, E_, E_, 0, 1, 0);

    // flash attention
    attn_mfma<<<B_ * H_ * (T_ / 64), 256, 0, stream>>>(qkB, vtG, attnB);

    // out projection + residual: x2 = x + attn @ Wo^T + bo  (512 blocks, 2/CU)
    gemm_bt<64, 128><<<dim3(E_ / 128, M_ / 64), 256, 0, stream>>>(
        attnB, WoB, bo, x, x2, nullptr, nullptr, nullptr, nullptr, nullptr,
        M_, E_, E_, E_, 0, 0, 0);

    // LN2
    ln_fwd<<<M_, 64, 0, stream>>>(h2B, x2, ln2g, ln2b);

    // FF1 + relu -> bf16  (1024 blocks, 3/CU at 48KB LDS, XCD swizzle)
    gemm_bt<128, 128><<<dim3(FF_ / 128, M_ / 128), 256, 0, stream>>>(
        h2B, W1B, b1, nullptr, nullptr, nullptr, nullptr, nullptr, rB, nullptr,
        M_, FF_, E_, E_, 1, 0, 1);

    // FF2 split-K=4 at 128x128 (ratio 2.0): grid (8,32,4) = 1024 blocks, 3/CU,
    // K=1024 each (ldk=4096). kz0 -> d_out (acc+bias+residual), kz1..3 -> P1..P3.
    gemm_bt<128, 128><<<dim3(E_ / 128, M_ / 128, 4), 256, 0, stream>>>(
        rB, W2B, b2, x2, (float*)d_out, P1, P2, P3, nullptr, nullptr,
        M_, E_, FF_ / 4, FF_, 0, 0, 1);

    // combine: d_out += P1 + P2 + P3  (16MB fp32 x 5 streams)
    addf3<<<(M_ * E_) / (256 * 4), 256, 0, stream>>>((float*)d_out, P1, P2, P3);
}